// Round 1
// baseline (703.441 us; speedup 1.0000x reference)
//
#include <hip/hip_runtime.h>

typedef __bf16 bf16_t;
typedef __bf16 bf16x8 __attribute__((ext_vector_type(8)));
typedef float f32x4 __attribute__((ext_vector_type(4)));
typedef float f32x2 __attribute__((ext_vector_type(2)));

#define N_NODES 50000
#define N_PAD   50048   // padded to multiple of 128 for 128-row GEMM tiles
#define N_EDGES 400000
#define D_IN    256
#define D_HID   512
#define D_OUT   128
#define N_LAYERS 4
#define ZROW    N_PAD                  // index of the always-zero hw row (dummy gathers)
#define CSR_CAP (N_EDGES + 3 * N_NODES + 64)  // padded-slot capacity

#define AS1 __attribute__((address_space(1)))
#define AS3 __attribute__((address_space(3)))

// ---------------- init: zero deg/cursor, dummy-fill csr, zero hw[ZROW], zero dinv pad ----

__global__ void init_misc(int* __restrict__ deg, int* __restrict__ cursor,
                          int* __restrict__ csr_src, float* __restrict__ dinv,
                          bf16_t* __restrict__ hw) {
    int idx = blockIdx.x * blockDim.x + threadIdx.x;
    if (idx < CSR_CAP) csr_src[idx] = ZROW;
    if (idx < N_NODES) { deg[idx] = 0; cursor[idx] = 0; }
    if (idx < N_PAD - N_NODES) dinv[N_NODES + idx] = 0.0f;
    if (idx < D_HID / 2) ((unsigned*)(hw + (size_t)ZROW * D_HID))[idx] = 0u;
}

// ---------------- fp32 -> bf16 conversion (flat, for x) ----------------

__global__ void f32_to_bf16(const float* __restrict__ in, bf16_t* __restrict__ out, int n) {
    int idx = (blockIdx.x * blockDim.x + threadIdx.x) * 4;
    if (idx + 3 < n) {
        float4 v = *reinterpret_cast<const float4*>(in + idx);
        bf16_t o[4] = {(bf16_t)v.x, (bf16_t)v.y, (bf16_t)v.z, (bf16_t)v.w};
        *reinterpret_cast<uint2*>(out + idx) = *reinterpret_cast<const uint2*>(o);
    } else {
        for (int j = idx; j < n; j++) out[j] = (bf16_t)in[j];
    }
}

// ---------------- batched fp32 [R][C] -> bf16 transposed [C][R] for all weights --------
// z: 0 = W1 (256x512), 1..4 = Wc layer (512x512), 5 = W2 (512x128)

__global__ void transpose_all(const float* __restrict__ W1, const float* __restrict__ Wc,
                              const float* __restrict__ W2, bf16_t* __restrict__ W1t,
                              bf16_t* __restrict__ Wct, bf16_t* __restrict__ W2t) {
    const float* in; bf16_t* out; int R, C;
    const int z = blockIdx.z;
    if (z == 0)      { in = W1; out = W1t; R = D_IN;  C = D_HID; }
    else if (z <= 4) { in = Wc + (size_t)(z - 1) * D_HID * D_HID;
                       out = Wct + (size_t)(z - 1) * D_HID * D_HID; R = D_HID; C = D_HID; }
    else             { in = W2; out = W2t; R = D_HID; C = D_OUT; }

    const int c0 = blockIdx.x * 32;
    const int r0 = blockIdx.y * 32;
    if (c0 >= C || r0 >= R) return;
    __shared__ float tile[32][33];
    for (int i = threadIdx.y; i < 32; i += 8)
        tile[i][threadIdx.x] = in[(size_t)(r0 + i) * C + c0 + threadIdx.x];
    __syncthreads();
    for (int i = threadIdx.y; i < 32; i += 8)
        out[(size_t)(c0 + i) * R + r0 + threadIdx.x] = (bf16_t)tile[threadIdx.x][i];
}

// ---------------- degree / padded CSR build ----------------

__global__ void count_deg(const int* __restrict__ dst, int* __restrict__ deg, int E) {
    int e = blockIdx.x * blockDim.x + threadIdx.x;
    if (e < E) atomicAdd(&deg[dst[e]], 1);
}

__global__ void scan_reduce(const int* __restrict__ deg, int* __restrict__ partial, int N) {
    __shared__ int red[256];
    int base = blockIdx.x * 1024;
    int s = 0;
    for (int i = threadIdx.x; i < 1024; i += 256) {
        int idx = base + i;
        s += (idx < N) ? ((deg[idx] + 3) & ~3) : 0;   // padded slots
    }
    red[threadIdx.x] = s;
    __syncthreads();
    for (int off = 128; off > 0; off >>= 1) {
        if (threadIdx.x < off) red[threadIdx.x] += red[threadIdx.x + off];
        __syncthreads();
    }
    if (threadIdx.x == 0) partial[blockIdx.x] = red[0];
}

__global__ void scan_partials(int* __restrict__ partial, int nb,
                              int* __restrict__ row_start, int N) {
    if (threadIdx.x == 0 && blockIdx.x == 0) {
        int acc = 0;
        for (int i = 0; i < nb; i++) { int v = partial[i]; partial[i] = acc; acc += v; }
        row_start[N] = acc;   // total padded slots
    }
}

__global__ void scan_chunks(const int* __restrict__ deg, const int* __restrict__ partial,
                            int* __restrict__ row_start, float* __restrict__ dinv, int N) {
    __shared__ int buf[2][1024];
    int t = threadIdx.x;
    int gid = blockIdx.x * 1024 + t;
    int d = (gid < N) ? deg[gid] : 0;
    int v = (gid < N) ? ((d + 3) & ~3) : 0;           // padded slots
    int cur = 0;
    buf[0][t] = v;
    __syncthreads();
    for (int off = 1; off < 1024; off <<= 1) {
        int nxt = cur ^ 1;
        int val = buf[cur][t];
        if (t >= off) val += buf[cur][t - off];
        buf[nxt][t] = val;
        cur = nxt;
        __syncthreads();
    }
    int incl = buf[cur][t];
    if (gid < N) {
        row_start[gid] = partial[blockIdx.x] + incl - v;  // exclusive
        dinv[gid] = rsqrtf((float)(d + 1));               // +1 self loop
    }
}

__global__ void fill_csr(const int* __restrict__ ei, int E,
                         const int* __restrict__ row_start,
                         int* __restrict__ cursor, int* __restrict__ csr_src) {
    int e = blockIdx.x * blockDim.x + threadIdx.x;
    if (e < E) {
        int s = ei[e];
        int d = ei[E + e];
        int pos = atomicAdd(&cursor[d], 1);
        csr_src[row_start[d] + pos] = s;
    }
}

// ---------------- GEMM: C = act(rowscale * (A @ BT^T) + bias) ----------------
// A: [M_pad][K] bf16. BT: [N][K] bf16 (pre-transposed). Block tile 128 x 128,
// 4 waves each 64x64 (acc 64 f32 -> AGPR), BK=64, global_load_lds width=16.
// LDS XOR-swizzled (chunk c of row r holds k-group c^(r&7)): conflict-free reads.
// XCD swizzle (gridDim.x==4): the 4 blocks sharing A-rows get ids == same (mod 8)
// so they land on the same XCD L2 -> A fetched into 1 L2 instead of 4.

template <bool F32OUT, bool RELU>
__global__ __launch_bounds__(256, 4) void gemm_tile(
    const bf16_t* __restrict__ A, const bf16_t* __restrict__ BT,
    const float* __restrict__ bias, const float* __restrict__ rowscale,
    void* __restrict__ Cv, int M, int N, int K)
{
    __shared__ __align__(16) char smem[32768];  // sA 16KB + sB 16KB; epilogue reuse
    bf16_t* sA = (bf16_t*)smem;
    bf16_t* sB = (bf16_t*)(smem + 128 * 128);
    bf16_t* sC = (bf16_t*)smem;                 // 64 x 136 bf16 = 17.4 KB

    int bxi, byi;
    if (gridDim.x == 4) {
        const int bid = blockIdx.y * 4 + blockIdx.x;     // dispatch-linear id
        const int T0 = (int)(gridDim.y * 4) & ~31;
        if (bid < T0) { int q = bid >> 5, r = bid & 31; byi = q * 8 + (r & 7); bxi = r >> 3; }
        else          { int t = bid - T0; byi = (T0 >> 2) + (t >> 2); bxi = t & 3; }
    } else { bxi = blockIdx.x; byi = blockIdx.y; }

    const int tid  = threadIdx.x;
    const int lane = tid & 63;
    const int wave = tid >> 6;
    const int bn = bxi * 128;
    const int bm = byi * 128;
    const int wm = (wave & 1) * 64;
    const int wn = (wave >> 1) * 64;
    const int lm = lane & 15;
    const int lq = lane >> 4;

    // staging: each 1KB wave-load covers 8 rows x 8 chunks; lane (r8,c8)
    const int r8 = lane >> 3;
    const int c8 = lane & 7;
    const int ksw = (c8 ^ r8) * 8;              // swizzled k-offset (elements)

    f32x4 acc[4][4] = {};

    const int nkb = K >> 6;
    for (int kb = 0; kb < nkb; kb++) {
        const int k0 = kb * 64;
#pragma unroll
        for (int r = 0; r < 4; r++) {               // A: 16 groups of 8 rows
            const int g = r * 4 + wave;
            __builtin_amdgcn_global_load_lds(
                (const AS1 unsigned int*)(A + (size_t)(bm + g * 8 + r8) * K + k0 + ksw),
                (AS3 unsigned int*)((AS3 char*)(AS3 bf16_t*)sA + g * 1024),
                16, 0, 0);
        }
#pragma unroll
        for (int r = 0; r < 4; r++) {               // B: 16 groups of 8 rows
            const int g = r * 4 + wave;
            __builtin_amdgcn_global_load_lds(
                (const AS1 unsigned int*)(BT + (size_t)(bn + g * 8 + r8) * K + k0 + ksw),
                (AS3 unsigned int*)((AS3 char*)(AS3 bf16_t*)sB + g * 1024),
                16, 0, 0);
        }
        __syncthreads();

#pragma unroll
        for (int s = 0; s < 2; s++) {               // two K=32 steps per BK=64
            bf16x8 af[4], bfr[4];
#pragma unroll
            for (int mt = 0; mt < 4; mt++) {
                const int R = wm + mt * 16 + lm;
                const int g = s * 4 + lq;
                af[mt] = *reinterpret_cast<bf16x8*>(&sA[R * 64 + ((g ^ (R & 7)) * 8)]);
            }
#pragma unroll
            for (int nt = 0; nt < 4; nt++) {
                const int R = wn + nt * 16 + lm;
                const int g = s * 4 + lq;
                bfr[nt] = *reinterpret_cast<bf16x8*>(&sB[R * 64 + ((g ^ (R & 7)) * 8)]);
            }
#pragma unroll
            for (int mt = 0; mt < 4; mt++)
#pragma unroll
                for (int nt = 0; nt < 4; nt++)
                    acc[mt][nt] = __builtin_amdgcn_mfma_f32_16x16x32_bf16(af[mt], bfr[nt], acc[mt][nt], 0, 0, 0);
        }
        __syncthreads();
    }

    if (!F32OUT) {
        // coalesced epilogue: 2 passes of 64 rows through LDS; sC row stride 136 elems
        const size_t rowbytes = (size_t)N * 2;
#pragma unroll
        for (int p = 0; p < 2; p++) {
            if (p) __syncthreads();
            if ((wave & 1) == p) {
#pragma unroll
                for (int nt = 0; nt < 4; nt++) {
                    const int col = wn + nt * 16 + lm;
                    const float bv = bias ? bias[bn + col] : 0.0f;
#pragma unroll
                    for (int mt = 0; mt < 4; mt++) {
#pragma unroll
                        for (int r = 0; r < 4; r++) {
                            const int lrow = mt * 16 + lq * 4 + r;
                            float v = acc[mt][nt][r] + bv;
                            if (rowscale) v *= rowscale[bm + p * 64 + lrow];
                            if (RELU) v = fmaxf(v, 0.0f);
                            sC[lrow * 136 + col] = (bf16_t)v;
                        }
                    }
                }
            }
            __syncthreads();
            char* outbase = (char*)Cv + (size_t)(bm + p * 64) * rowbytes + (size_t)bn * 2;
#pragma unroll
            for (int j = 0; j < 4; j++) {
                const int idx = j * 4096 + tid * 16;
                const int row = idx >> 8;            // 256 data bytes per row
                const int colb = idx & 255;
                *reinterpret_cast<uint4*>(outbase + (size_t)row * rowbytes + colb) =
                    *reinterpret_cast<const uint4*>((char*)sC + (size_t)row * 272 + colb);
            }
        }
    } else {
        // scattered epilogue (dnn2, fp32 out): C/D layout col=lane&15, row=lq*4+reg
#pragma unroll
        for (int nt = 0; nt < 4; nt++) {
            const int col = bn + wn + nt * 16 + lm;
            const float bv = bias ? bias[col] : 0.0f;
#pragma unroll
            for (int mt = 0; mt < 4; mt++) {
#pragma unroll
                for (int r = 0; r < 4; r++) {
                    const int row = bm + wm + mt * 16 + lq * 4 + r;
                    if (row < M) {
                        float v = acc[mt][nt][r] + bv;
                        if (rowscale) v *= rowscale[row];
                        if (RELU) v = fmaxf(v, 0.0f);
                        ((float*)Cv)[(size_t)row * N + col] = v;
                    }
                }
            }
        }
    }
}

// ---------------- aggregation ----------------
// hw is pre-scaled: hw[s] = dinv[s] * (h W)[s]. Slots padded to x4, dummies -> ZROW (zeros).
// h_out[n] = dinv[n] * ( hw[n] + sum_slots hw[s] ) + bias
//
// MLP-restructured: each wave handles TWO consecutive nodes (their padded CSR
// ranges are adjacent -> one combined slot stream, total multiple of 4).
// 8 gathers (16B/lane, 1KB/wave each) in flight per chunk; self-rows + first
// index chunk issued up-front; next chunk's indices prefetched on the scalar
// path (s_load, lgkmcnt) so the vmcnt gather queue never drains on index
// latency. readfirstlane forces wave-uniform values into SGPRs so row_start /
// csr index loads scalarize. Since per-node padding is x4, every 4-slot group
// belongs entirely to one node -> accumulator routing is a uniform scalar
// branch (no register-indexed arrays).

#define ACCUM(accv, uvec) do {                                        \
    const unsigned* _w = reinterpret_cast<const unsigned*>(&(uvec));  \
    _Pragma("unroll")                                                 \
    for (int _j = 0; _j < 4; _j++) {                                  \
        f32x2 _v;                                                     \
        _v[0] = __uint_as_float(_w[_j] << 16);                        \
        _v[1] = __uint_as_float(_w[_j] & 0xffff0000u);                \
        (accv)[_j] += _v;                                             \
    }                                                                 \
} while (0)

__global__ __launch_bounds__(256) void aggregate(
    const bf16_t* __restrict__ hw, const float* __restrict__ dinv,
    const int* __restrict__ row_start, const int* __restrict__ csr_src,
    const float* __restrict__ bias, bf16_t* __restrict__ h_out, int N)
{
    // wave id (uniform) -> SGPR; wave handles nodes {2w, 2w+1}. N is even.
    const int w = __builtin_amdgcn_readfirstlane(blockIdx.x * 4 + (threadIdx.x >> 6));
    const int na = w * 2;
    if (na >= N) return;
    const int nb = na + 1;
    const int lane = threadIdx.x & 63;
    const char* hwb = (const char*)hw + lane * 16;

    const int beg   = row_start[na];
    const int mid   = row_start[nb];
    const int end   = row_start[nb + 1];
    const int cnt_a = mid - beg;         // multiple of 4
    const int total = end - beg;         // multiple of 4
    const int* ip   = csr_src + beg;

    // issue both self-row gathers + first index chunk immediately
    uint4 sa = *reinterpret_cast<const uint4*>(hwb + ((size_t)na << 10));
    uint4 sb = *reinterpret_cast<const uint4*>(hwb + ((size_t)nb << 10));
    int4 c0, c1;
    if (total > 0) c0 = *reinterpret_cast<const int4*>(ip);
    if (total > 4) c1 = *reinterpret_cast<const int4*>(ip + 4);

    // init accumulators from the (pre-scaled) self terms
    f32x2 acc_a[4], acc_b[4];
    {
        const unsigned* wa = reinterpret_cast<const unsigned*>(&sa);
        const unsigned* wb = reinterpret_cast<const unsigned*>(&sb);
#pragma unroll
        for (int j = 0; j < 4; j++) {
            acc_a[j][0] = __uint_as_float(wa[j] << 16);
            acc_a[j][1] = __uint_as_float(wa[j] & 0xffff0000u);
            acc_b[j][0] = __uint_as_float(wb[j] << 16);
            acc_b[j][1] = __uint_as_float(wb[j] & 0xffff0000u);
        }
    }

    int i = 0;
    while (i < total) {
        const int rem = total - i;       // multiple of 4, >= 4
        uint4 u[8];
        u[0] = *reinterpret_cast<const uint4*>(hwb + ((size_t)c0.x << 10));
        u[1] = *reinterpret_cast<const uint4*>(hwb + ((size_t)c0.y << 10));
        u[2] = *reinterpret_cast<const uint4*>(hwb + ((size_t)c0.z << 10));
        u[3] = *reinterpret_cast<const uint4*>(hwb + ((size_t)c0.w << 10));
        if (rem > 4) {
            u[4] = *reinterpret_cast<const uint4*>(hwb + ((size_t)c1.x << 10));
            u[5] = *reinterpret_cast<const uint4*>(hwb + ((size_t)c1.y << 10));
            u[6] = *reinterpret_cast<const uint4*>(hwb + ((size_t)c1.z << 10));
            u[7] = *reinterpret_cast<const uint4*>(hwb + ((size_t)c1.w << 10));
        }
        // prefetch next chunk's indices (scalar path; overlaps gather latency)
        if (rem > 8) {
            c0 = *reinterpret_cast<const int4*>(ip + i + 8);
            if (rem > 12) c1 = *reinterpret_cast<const int4*>(ip + i + 12);
        }
        // route 4-slot groups (each group wholly belongs to one node)
        if (i < cnt_a) { ACCUM(acc_a, u[0]); ACCUM(acc_a, u[1]); ACCUM(acc_a, u[2]); ACCUM(acc_a, u[3]); }
        else           { ACCUM(acc_b, u[0]); ACCUM(acc_b, u[1]); ACCUM(acc_b, u[2]); ACCUM(acc_b, u[3]); }
        if (rem > 4) {
            if (i + 4 < cnt_a) { ACCUM(acc_a, u[4]); ACCUM(acc_a, u[5]); ACCUM(acc_a, u[6]); ACCUM(acc_a, u[7]); }
            else               { ACCUM(acc_b, u[4]); ACCUM(acc_b, u[5]); ACCUM(acc_b, u[6]); ACCUM(acc_b, u[7]); }
        }
        i += 8;
    }

    const int f = lane * 8;
    const float4 bv0 = *reinterpret_cast<const float4*>(bias + f);
    const float4 bv1 = *reinterpret_cast<const float4*>(bias + f + 4);
    const float bvs[8] = {bv0.x, bv0.y, bv0.z, bv0.w, bv1.x, bv1.y, bv1.z, bv1.w};
    const float da = dinv[na];
    const float db = dinv[nb];
    bf16_t oa[8], ob[8];
#pragma unroll
    for (int j = 0; j < 4; j++) {
        oa[2 * j]     = (bf16_t)(fmaf(da, acc_a[j][0], bvs[2 * j]));
        oa[2 * j + 1] = (bf16_t)(fmaf(da, acc_a[j][1], bvs[2 * j + 1]));
        ob[2 * j]     = (bf16_t)(fmaf(db, acc_b[j][0], bvs[2 * j]));
        ob[2 * j + 1] = (bf16_t)(fmaf(db, acc_b[j][1], bvs[2 * j + 1]));
    }
    *reinterpret_cast<uint4*>(h_out + (size_t)na * D_HID + f) = *reinterpret_cast<const uint4*>(oa);
    *reinterpret_cast<uint4*>(h_out + (size_t)nb * D_HID + f) = *reinterpret_cast<const uint4*>(ob);
}

// ---------------- orchestration ----------------

extern "C" void kernel_launch(void* const* d_in, const int* in_sizes, int n_in,
                              void* d_out, int out_size, void* d_ws, size_t ws_size,
                              hipStream_t stream) {
    const int N = N_NODES, E = N_EDGES;

    const float* x  = (const float*)d_in[0];
    const int*   ei = (const int*)d_in[1];
    const float* W1 = (const float*)d_in[2];
    const float* b1 = (const float*)d_in[3];
    const float* Wc = (const float*)d_in[4];
    const float* bc = (const float*)d_in[5];
    const float* W2 = (const float*)d_in[6];
    const float* b2 = (const float*)d_in[7];
    float* out = (float*)d_out;

    char* ws = (char*)d_ws;
    size_t off = 0;
    auto alloc = [&](size_t bytes) -> void* {
        void* p = ws + off;
        off += (bytes + 255) & ~(size_t)255;
        return p;
    };
    int*    deg       = (int*)alloc((size_t)N * 4);
    int*    cursor    = (int*)alloc((size_t)N * 4);
    int*    row_start = (int*)alloc((size_t)(N + 1) * 4);
    int*    partial   = (int*)alloc(256 * 4);
    float*  dinv      = (float*)alloc((size_t)N_PAD * 4);
    int*    csr_src   = (int*)alloc((size_t)CSR_CAP * 4);
    bf16_t* h         = (bf16_t*)alloc((size_t)N_PAD * D_HID * 2);
    bf16_t* hw        = (bf16_t*)alloc((size_t)(N_PAD + 1) * D_HID * 2);  // +1: ZROW
    bf16_t* xb        = (bf16_t*)alloc((size_t)N_PAD * D_IN * 2);
    bf16_t* W1t       = (bf16_t*)alloc((size_t)D_HID * D_IN * 2);
    bf16_t* Wct       = (bf16_t*)alloc((size_t)N_LAYERS * D_HID * D_HID * 2);
    bf16_t* W2t       = (bf16_t*)alloc((size_t)D_OUT * D_HID * 2);

    // init (zero deg/cursor, dummy csr fill, zero hw[ZROW], zero dinv pad)
    init_misc<<<(CSR_CAP + 255) / 256, 256, 0, stream>>>(deg, cursor, csr_src, dinv, hw);

    // conversions
    {
        int n = N * D_IN;
        f32_to_bf16<<<(n / 4 + 255) / 256, 256, 0, stream>>>(x, xb, n);
        transpose_all<<<dim3(16, 16, 6), dim3(32, 8), 0, stream>>>(W1, Wc, W2, W1t, Wct, W2t);
    }

    // padded CSR build
    count_deg<<<(E + 255) / 256, 256, 0, stream>>>(ei + E, deg, E);
    const int nch = (N + 1023) / 1024;
    scan_reduce<<<nch, 256, 0, stream>>>(deg, partial, N);
    scan_partials<<<1, 64, 0, stream>>>(partial, nch, row_start, N);
    scan_chunks<<<nch, 1024, 0, stream>>>(deg, partial, row_start, dinv, N);
    fill_csr<<<(E + 255) / 256, 256, 0, stream>>>(ei, E, row_start, cursor, csr_src);

    const dim3 blk(256);
    const int mg = N_PAD / 128;  // 391

    // dnn1: h = relu(x @ W1 + b1)
    gemm_tile<false, true><<<dim3(D_HID / 128, mg), blk, 0, stream>>>(
        xb, W1t, b1, nullptr, h, N_PAD, D_HID, D_IN);

    // GCN layers: hw = dinv .* (h @ Wc[i]); h = dinv .* (hw[self] + gather-sum) + bc[i]
    const int nwaves = N / 2;                       // 2 nodes per wave
    for (int i = 0; i < N_LAYERS; i++) {
        gemm_tile<false, false><<<dim3(D_HID / 128, mg), blk, 0, stream>>>(
            h, Wct + (size_t)i * D_HID * D_HID, nullptr, dinv, hw, N_PAD, D_HID, D_HID);
        aggregate<<<(nwaves + 3) / 4, 256, 0, stream>>>(hw, dinv, row_start, csr_src,
                                                        bc + (size_t)i * D_HID, h, N);
    }

    // dnn2: out = h @ W2 + b2 (fp32 out)
    gemm_tile<true, false><<<dim3(D_OUT / 128, mg), blk, 0, stream>>>(
        h, W2t, b2, nullptr, out, N, D_OUT, D_HID);
}